// Round 1
// baseline (7057.194 us; speedup 1.0000x reference)
//
#include <hip/hip_runtime.h>
#include <hip/hip_bf16.h>

#define VOCAB 32000
#define EMBED 512
#define HID   1024
#define BB    16
#define TT    256
#define MROWS (BB*TT)   // 4096

// ---------------------------------------------------------------------------
// Embedding gather: x[m][:] = emb[tok[m]][:]
// ---------------------------------------------------------------------------
__global__ __launch_bounds__(128) void gather_x(const int* __restrict__ tok,
                                                const float* __restrict__ emb,
                                                float* __restrict__ x) {
    int row = blockIdx.x;
    int t = tok[row];
    const float4* src = (const float4*)(emb + (size_t)t * EMBED);
    float4* dst = (float4*)(x + (size_t)row * EMBED);
    dst[threadIdx.x] = src[threadIdx.x];   // 128 threads * 16B = 2KB row
}

// ---------------------------------------------------------------------------
// Generic f32 GEMM: C[M][N] = A[M][K] * B[N][K]^T + bias[N]  (optional ReLU)
// 128x128 tile, BK=16, 256 threads, 8x8 per-thread microtile.
// M,N multiples of 128; K multiple of 16 (true for all 3 uses).
// ---------------------------------------------------------------------------
template <int RELU>
__global__ __launch_bounds__(256) void gemm_bt(const float* __restrict__ A,
                                               const float* __restrict__ B,
                                               const float* __restrict__ bias,
                                               float* __restrict__ C,
                                               int M, int N, int K) {
    const int BM = 128, BN = 128, BK = 16;
    __shared__ float As[BK][BM + 4];
    __shared__ float Bs[BK][BN + 4];

    int bm = blockIdx.x * BM;
    int bn = blockIdx.y * BN;
    int tid = threadIdx.x;
    int tx = tid & 15, ty = tid >> 4;

    // loader mapping: 256 threads load 128 rows x 16 k (one float4 each, twice)
    int lrow = tid >> 2;            // 0..63
    int lk   = (tid & 3) * 4;       // 0,4,8,12

    const float* Ab = A + (size_t)bm * K;
    const float* Bb = B + (size_t)bn * K;

    float acc[8][8];
#pragma unroll
    for (int i = 0; i < 8; i++)
#pragma unroll
        for (int j = 0; j < 8; j++) acc[i][j] = 0.f;

    for (int k0 = 0; k0 < K; k0 += BK) {
        float4 a0 = *(const float4*)(Ab + (size_t)lrow * K + k0 + lk);
        float4 a1 = *(const float4*)(Ab + (size_t)(lrow + 64) * K + k0 + lk);
        float4 b0 = *(const float4*)(Bb + (size_t)lrow * K + k0 + lk);
        float4 b1 = *(const float4*)(Bb + (size_t)(lrow + 64) * K + k0 + lk);
        __syncthreads();   // protect previous iteration's LDS reads
        As[lk + 0][lrow] = a0.x; As[lk + 1][lrow] = a0.y;
        As[lk + 2][lrow] = a0.z; As[lk + 3][lrow] = a0.w;
        As[lk + 0][lrow + 64] = a1.x; As[lk + 1][lrow + 64] = a1.y;
        As[lk + 2][lrow + 64] = a1.z; As[lk + 3][lrow + 64] = a1.w;
        Bs[lk + 0][lrow] = b0.x; Bs[lk + 1][lrow] = b0.y;
        Bs[lk + 2][lrow] = b0.z; Bs[lk + 3][lrow] = b0.w;
        Bs[lk + 0][lrow + 64] = b1.x; Bs[lk + 1][lrow + 64] = b1.y;
        Bs[lk + 2][lrow + 64] = b1.z; Bs[lk + 3][lrow + 64] = b1.w;
        __syncthreads();
#pragma unroll
        for (int k = 0; k < BK; k++) {
            float a[8], b[8];
            *(float4*)&a[0] = *(const float4*)&As[k][ty * 8];
            *(float4*)&a[4] = *(const float4*)&As[k][ty * 8 + 4];
            *(float4*)&b[0] = *(const float4*)&Bs[k][tx * 8];
            *(float4*)&b[4] = *(const float4*)&Bs[k][tx * 8 + 4];
#pragma unroll
            for (int i = 0; i < 8; i++)
#pragma unroll
                for (int j = 0; j < 8; j++) acc[i][j] += a[i] * b[j];
        }
    }

#pragma unroll
    for (int i = 0; i < 8; i++) {
        size_t m = bm + ty * 8 + i;
#pragma unroll
        for (int j = 0; j < 8; j++) {
            int n = bn + tx * 8 + j;
            float v = acc[i][j] + bias[n];
            if (RELU) v = fmaxf(v, 0.f);
            C[m * N + n] = v;
        }
    }
}

// ---------------------------------------------------------------------------
// One GRU time step. Grid = 256 blocks; block owns j0 = blockIdx.x*4 .. +3.
// Wave w (of 4) owns column j = j0 + w for all 16 batches.
// h_prev (16x1024 = 64KB) staged in LDS; the 3 W_hh rows for this j live in
// registers (each W_hh row is read exactly once per step, globally).
// ---------------------------------------------------------------------------
__global__ __launch_bounds__(256) void gru_step(const float* __restrict__ gi,
                                                const float* __restrict__ W_hh,
                                                const float* __restrict__ b_hh,
                                                const float* __restrict__ h_in,
                                                float* __restrict__ h_out,
                                                float* __restrict__ hs,
                                                float* __restrict__ hid_out,
                                                int t) {
    __shared__ float hsm[BB * HID];   // 64KB
    int tid = threadIdx.x;

    // stage h_in into LDS (4096 float4 / 256 threads = 16 each, coalesced)
    const float4* hi4 = (const float4*)h_in;
    float4* hm4 = (float4*)hsm;
#pragma unroll
    for (int i = 0; i < 16; i++) hm4[tid + i * 256] = hi4[tid + i * 256];

    int wave = tid >> 6, lane = tid & 63;
    int j = blockIdx.x * 4 + wave;

    // gate rows r/z/n for column j -> registers (coalesced global loads)
    const float* Wr = W_hh + (size_t)(0 * HID + j) * HID;
    const float* Wz = W_hh + (size_t)(1 * HID + j) * HID;
    const float* Wn = W_hh + (size_t)(2 * HID + j) * HID;
    float4 wr[4], wz[4], wn[4];
#pragma unroll
    for (int i = 0; i < 4; i++) {
        wr[i] = *(const float4*)(Wr + lane * 4 + i * 256);
        wz[i] = *(const float4*)(Wz + lane * 4 + i * 256);
        wn[i] = *(const float4*)(Wn + lane * 4 + i * 256);
    }
    float bhr = b_hh[j], bhz = b_hh[HID + j], bhn = b_hh[2 * HID + j];

    __syncthreads();

    float my_hr = 0.f, my_hz = 0.f, my_hn = 0.f;
    for (int b = 0; b < BB; b++) {
        const float4* hb = (const float4*)(hsm + b * HID);
        float sr = 0.f, sz = 0.f, sn = 0.f;
#pragma unroll
        for (int i = 0; i < 4; i++) {
            float4 h4 = hb[lane + i * 64];
            sr += wr[i].x * h4.x + wr[i].y * h4.y + wr[i].z * h4.z + wr[i].w * h4.w;
            sz += wz[i].x * h4.x + wz[i].y * h4.y + wz[i].z * h4.z + wz[i].w * h4.w;
            sn += wn[i].x * h4.x + wn[i].y * h4.y + wn[i].z * h4.z + wn[i].w * h4.w;
        }
#pragma unroll
        for (int off = 32; off; off >>= 1) {
            sr += __shfl_xor(sr, off);
            sz += __shfl_xor(sz, off);
            sn += __shfl_xor(sn, off);
        }
        my_hr = (lane == b) ? sr : my_hr;
        my_hz = (lane == b) ? sz : my_hz;
        my_hn = (lane == b) ? sn : my_hn;
    }

    if (lane < BB) {
        int b = lane;
        size_t girow = ((size_t)b * TT + t) * (3 * HID);
        float ir  = gi[girow + j];
        float iz  = gi[girow + HID + j];
        float inn = gi[girow + 2 * HID + j];
        float r = 1.f / (1.f + __expf(-(ir + my_hr + bhr)));
        float z = 1.f / (1.f + __expf(-(iz + my_hz + bhz)));
        float n = tanhf(inn + r * (my_hn + bhn));
        float hprev = hsm[b * HID + j];
        float hnew = (1.f - z) * n + z * hprev;
        h_out[b * HID + j] = hnew;
        hs[((size_t)b * TT + t) * HID + j] = hnew;
        if (hid_out) hid_out[b * HID + j] = hnew;
    }
}

// ---------------------------------------------------------------------------
// In-place log_softmax over the last dim (32000) of out[4096][32000].
// ---------------------------------------------------------------------------
__global__ __launch_bounds__(256) void logsoftmax_rows(float* __restrict__ out) {
    int row = blockIdx.x;
    float* p = out + (size_t)row * VOCAB;
    int tid = threadIdx.x;
    __shared__ float red[4];

    float m = -3.4e38f;
    for (int i = tid; i < VOCAB; i += 256) m = fmaxf(m, p[i]);
#pragma unroll
    for (int off = 32; off; off >>= 1) m = fmaxf(m, __shfl_xor(m, off));
    if ((tid & 63) == 0) red[tid >> 6] = m;
    __syncthreads();
    m = fmaxf(fmaxf(red[0], red[1]), fmaxf(red[2], red[3]));
    __syncthreads();

    float s = 0.f;
    for (int i = tid; i < VOCAB; i += 256) s += __expf(p[i] - m);
#pragma unroll
    for (int off = 32; off; off >>= 1) s += __shfl_xor(s, off);
    if ((tid & 63) == 0) red[tid >> 6] = s;
    __syncthreads();
    s = red[0] + red[1] + red[2] + red[3];

    float lse = m + __logf(s);
    for (int i = tid; i < VOCAB; i += 256) p[i] = p[i] - lse;
}

// ---------------------------------------------------------------------------
extern "C" void kernel_launch(void* const* d_in, const int* in_sizes, int n_in,
                              void* d_out, int out_size, void* d_ws, size_t ws_size,
                              hipStream_t stream) {
    const int*   tok  = (const int*)d_in[0];
    const float* emb  = (const float*)d_in[1];
    const float* W_ih = (const float*)d_in[2];
    const float* W_hh = (const float*)d_in[3];
    const float* b_ih = (const float*)d_in[4];
    const float* b_hh = (const float*)d_in[5];
    const float* W1   = (const float*)d_in[6];
    const float* b1   = (const float*)d_in[7];
    const float* W2   = (const float*)d_in[8];
    const float* b2   = (const float*)d_in[9];

    float* out = (float*)d_out;                       // [4096][32000] log-probs
    float* hid = out + (size_t)MROWS * VOCAB;         // [1][16][1024]

    // workspace layout (f32): x | gi | hs | y | hA | hB   (~92.4 MB)
    float* x     = (float*)d_ws;                          // 4096*512
    float* gi    = x + (size_t)MROWS * EMBED;             // 4096*3072
    float* hsbuf = gi + (size_t)MROWS * 3 * HID;          // 4096*1024
    float* ybuf  = hsbuf + (size_t)MROWS * HID;           // 4096*1024
    float* hA    = ybuf + (size_t)MROWS * HID;            // 16*1024
    float* hB    = hA + BB * HID;                         // 16*1024

    // 1. embedding gather
    gather_x<<<MROWS, 128, 0, stream>>>(tok, emb, x);

    // 2. gi = x @ W_ih^T + b_ih     [4096, 3072]
    gemm_bt<0><<<dim3(MROWS / 128, (3 * HID) / 128), 256, 0, stream>>>(
        x, W_ih, b_ih, gi, MROWS, 3 * HID, EMBED);

    // 3. GRU scan (h0 = 0)
    hipMemsetAsync(hA, 0, (size_t)BB * HID * sizeof(float), stream);
    for (int t = 0; t < TT; ++t) {
        const float* hin = (t & 1) ? hB : hA;
        float* hout      = (t & 1) ? hA : hB;
        gru_step<<<HID / 4, 256, 0, stream>>>(gi, W_hh, b_hh, hin, hout, hsbuf,
                                              (t == TT - 1) ? hid : nullptr, t);
    }

    // 4. y = relu(hs @ W1^T + b1)   [4096, 1024]
    gemm_bt<1><<<dim3(MROWS / 128, HID / 128), 256, 0, stream>>>(
        hsbuf, W1, b1, ybuf, MROWS, HID, HID);

    // 5. logits = y @ W2^T + b2  -> d_out   [4096, 32000]
    gemm_bt<0><<<dim3(MROWS / 128, VOCAB / 128), 256, 0, stream>>>(
        ybuf, W2, b2, out, MROWS, VOCAB, HID);

    // 6. in-place log_softmax over vocab
    logsoftmax_rows<<<MROWS, 256, 0, stream>>>(out);
}

// Round 2
// 4374.435 us; speedup vs baseline: 1.6133x; 1.6133x over previous
//
#include <hip/hip_runtime.h>
#include <hip/hip_bf16.h>

#define VOCAB 32000
#define EMBED 512
#define HID   1024
#define BB    16
#define TT    256
#define MROWS (BB*TT)   // 4096

typedef __attribute__((ext_vector_type(8))) short bf16x8;
typedef __attribute__((ext_vector_type(4))) float f32x4;

static __device__ __forceinline__ short f2bf(float f) {
    __hip_bfloat16 h = __float2bfloat16(f);
    return *reinterpret_cast<short*>(&h);
}
static __device__ __forceinline__ float bf2f(short s) {
    __hip_bfloat16 h = *reinterpret_cast<__hip_bfloat16*>(&s);
    return __bfloat162float(h);
}

// ---------------------------------------------------------------------------
// Embedding gather + hi/lo bf16 split: xp[m][0..511]=hi, xp[m][512..1023]=lo
// ---------------------------------------------------------------------------
__global__ __launch_bounds__(64) void gather_split(const int* __restrict__ tok,
                                                   const float* __restrict__ emb,
                                                   short* __restrict__ xp) {
    int row = blockIdx.x;
    int t = tok[row];
    const float4* src = (const float4*)(emb + (size_t)t * EMBED);
    int l = threadIdx.x;
#pragma unroll
    for (int i = 0; i < 2; i++) {
        float4 e = src[l + i * 64];
        int k = (l + i * 64) * 4;
        float ev[4] = {e.x, e.y, e.z, e.w};
        short hi[4], lo[4];
#pragma unroll
        for (int q = 0; q < 4; q++) {
            hi[q] = f2bf(ev[q]);
            lo[q] = f2bf(ev[q] - bf2f(hi[q]));
        }
        short4 h4 = make_short4(hi[0], hi[1], hi[2], hi[3]);
        short4 l4 = make_short4(lo[0], lo[1], lo[2], lo[3]);
        *(short4*)(xp + (size_t)row * 1024 + k) = h4;
        *(short4*)(xp + (size_t)row * 1024 + 512 + k) = l4;
    }
}

// ---------------------------------------------------------------------------
// MFMA GEMM: C[M][N] = A[M][K](bf16, optionally hi/lo split over KA=2K)
//                      * B[N][K](f32, converted to bf16 during staging)^T + bias
// 128x128 tile, BK=64 (2 MFMA k-steps of 16x16x32), 4 waves, 4x4 frags/wave.
// LDS XOR-swizzled (chunk ^= row&7) -> conflict-free ds_read_b128 (T2/G4).
// EPI: 0 = f32 out (+bias), 1 = relu + bf16 out (+bias).
// ---------------------------------------------------------------------------
template <int SPLITA, int EPI>
__global__ __launch_bounds__(256) void gemm_mf(const short* __restrict__ A,
                                               const float* __restrict__ B,
                                               const float* __restrict__ bias,
                                               float* __restrict__ Cf,
                                               short* __restrict__ Cb,
                                               int M, int N, int K) {
    const int KA = (SPLITA + 1) * K;
    __shared__ short As[(SPLITA + 1) * 8192];   // [halves][128][64] bf16
    __shared__ short Bs[8192];                  // [128][64] bf16

    int tid = threadIdx.x;
    int lane = tid & 63, wave = tid >> 6;
    int wr = wave >> 1, wc = wave & 1;          // 2x2 waves of 64x64
    int l15 = lane & 15, l4 = lane >> 4;
    int bm = blockIdx.x * 128, bn = blockIdx.y * 128;

    int lrow = tid >> 3;        // loader: 32 rows per round
    int lc = tid & 7;           // chunk (8 bf16 / 16B) within row

    f32x4 acc[4][4];
#pragma unroll
    for (int i = 0; i < 4; i++)
#pragma unroll
        for (int j = 0; j < 4; j++) acc[i][j] = (f32x4){0.f, 0.f, 0.f, 0.f};

    for (int k0 = 0; k0 < K; k0 += 64) {
        // ---- issue global loads (overlap with previous MFMA phase) ----
        bf16x8 areg[SPLITA + 1][4];
        float4 breg[4][2];
#pragma unroll
        for (int h = 0; h <= SPLITA; h++)
#pragma unroll
            for (int r = 0; r < 4; r++) {
                int row = lrow + r * 32;
                areg[h][r] = *(const bf16x8*)(A + (size_t)(bm + row) * KA + h * K + k0 + lc * 8);
            }
#pragma unroll
        for (int r = 0; r < 4; r++) {
            int row = lrow + r * 32;
            const float* bp = B + (size_t)(bn + row) * K + k0 + lc * 8;
            breg[r][0] = *(const float4*)bp;
            breg[r][1] = *(const float4*)(bp + 4);
        }
        __syncthreads();   // previous compute phase's LDS reads complete
        // ---- LDS writes (XOR-swizzled) ----
#pragma unroll
        for (int h = 0; h <= SPLITA; h++)
#pragma unroll
            for (int r = 0; r < 4; r++) {
                int row = lrow + r * 32;
                *(bf16x8*)((char*)As + h * 16384 + row * 128 + ((lc ^ (row & 7)) << 4)) = areg[h][r];
            }
#pragma unroll
        for (int r = 0; r < 4; r++) {
            int row = lrow + r * 32;
            float tmp[8];
            *(float4*)&tmp[0] = breg[r][0];
            *(float4*)&tmp[4] = breg[r][1];
            bf16x8 w;
#pragma unroll
            for (int q = 0; q < 8; q++) w[q] = f2bf(tmp[q]);
            *(bf16x8*)((char*)Bs + row * 128 + ((lc ^ (row & 7)) << 4)) = w;
        }
        __syncthreads();   // tile ready
        // ---- compute ----
#pragma unroll
        for (int kk = 0; kk < 2; kk++) {
            bf16x8 af[SPLITA + 1][4], bfr[4];
            int cc = kk * 4 + l4;
#pragma unroll
            for (int f = 0; f < 4; f++) {
                int ar = wr * 64 + f * 16 + l15;
#pragma unroll
                for (int h = 0; h <= SPLITA; h++)
                    af[h][f] = *(const bf16x8*)((char*)As + h * 16384 + ar * 128 + ((cc ^ (ar & 7)) << 4));
                int br = wc * 64 + f * 16 + l15;
                bfr[f] = *(const bf16x8*)((char*)Bs + br * 128 + ((cc ^ (br & 7)) << 4));
            }
#pragma unroll
            for (int fm = 0; fm < 4; fm++)
#pragma unroll
                for (int fn = 0; fn < 4; fn++) {
                    acc[fm][fn] = __builtin_amdgcn_mfma_f32_16x16x32_bf16(af[0][fm], bfr[fn], acc[fm][fn], 0, 0, 0);
                    if constexpr (SPLITA)
                        acc[fm][fn] = __builtin_amdgcn_mfma_f32_16x16x32_bf16(af[SPLITA][fm], bfr[fn], acc[fm][fn], 0, 0, 0);
                }
        }
    }

    // ---- epilogue: C/D layout col=lane&15, row=(lane>>4)*4+reg (m89) ----
    float bsv[4];
#pragma unroll
    for (int fn = 0; fn < 4; fn++) bsv[fn] = bias[bn + wc * 64 + fn * 16 + l15];
#pragma unroll
    for (int fm = 0; fm < 4; fm++)
#pragma unroll
        for (int fn = 0; fn < 4; fn++) {
            int col = bn + wc * 64 + fn * 16 + l15;
#pragma unroll
            for (int r = 0; r < 4; r++) {
                int row = bm + wr * 64 + fm * 16 + l4 * 4 + r;
                float v = acc[fm][fn][r] + bsv[fn];
                if constexpr (EPI == 1) {
                    v = fmaxf(v, 0.f);
                    Cb[(size_t)row * N + col] = f2bf(v);
                } else {
                    Cf[(size_t)row * N + col] = v;
                }
            }
        }
}

// ---------------------------------------------------------------------------
// One GRU time step (as round-1, but hs is written as split-bf16 for lin1).
// ---------------------------------------------------------------------------
__global__ __launch_bounds__(256) void gru_step(const float* __restrict__ gi,
                                                const float* __restrict__ W_hh,
                                                const float* __restrict__ b_hh,
                                                const float* __restrict__ h_in,
                                                float* __restrict__ h_out,
                                                short* __restrict__ hs_s,
                                                float* __restrict__ hid_out,
                                                int t) {
    __shared__ float hsm[BB * HID];   // 64KB
    int tid = threadIdx.x;

    const float4* hi4 = (const float4*)h_in;
    float4* hm4 = (float4*)hsm;
#pragma unroll
    for (int i = 0; i < 16; i++) hm4[tid + i * 256] = hi4[tid + i * 256];

    int wave = tid >> 6, lane = tid & 63;
    int j = blockIdx.x * 4 + wave;

    const float* Wr = W_hh + (size_t)(0 * HID + j) * HID;
    const float* Wz = W_hh + (size_t)(1 * HID + j) * HID;
    const float* Wn = W_hh + (size_t)(2 * HID + j) * HID;
    float4 wr[4], wz[4], wn[4];
#pragma unroll
    for (int i = 0; i < 4; i++) {
        wr[i] = *(const float4*)(Wr + lane * 4 + i * 256);
        wz[i] = *(const float4*)(Wz + lane * 4 + i * 256);
        wn[i] = *(const float4*)(Wn + lane * 4 + i * 256);
    }
    float bhr = b_hh[j], bhz = b_hh[HID + j], bhn = b_hh[2 * HID + j];

    __syncthreads();

    float my_hr = 0.f, my_hz = 0.f, my_hn = 0.f;
    for (int b = 0; b < BB; b++) {
        const float4* hb = (const float4*)(hsm + b * HID);
        float sr = 0.f, sz = 0.f, sn = 0.f;
#pragma unroll
        for (int i = 0; i < 4; i++) {
            float4 h4 = hb[lane + i * 64];
            sr += wr[i].x * h4.x + wr[i].y * h4.y + wr[i].z * h4.z + wr[i].w * h4.w;
            sz += wz[i].x * h4.x + wz[i].y * h4.y + wz[i].z * h4.z + wz[i].w * h4.w;
            sn += wn[i].x * h4.x + wn[i].y * h4.y + wn[i].z * h4.z + wn[i].w * h4.w;
        }
#pragma unroll
        for (int off = 32; off; off >>= 1) {
            sr += __shfl_xor(sr, off);
            sz += __shfl_xor(sz, off);
            sn += __shfl_xor(sn, off);
        }
        my_hr = (lane == b) ? sr : my_hr;
        my_hz = (lane == b) ? sz : my_hz;
        my_hn = (lane == b) ? sn : my_hn;
    }

    if (lane < BB) {
        int b = lane;
        size_t girow = ((size_t)b * TT + t) * (3 * HID);
        float ir  = gi[girow + j];
        float iz  = gi[girow + HID + j];
        float inn = gi[girow + 2 * HID + j];
        float r = 1.f / (1.f + __expf(-(ir + my_hr + bhr)));
        float z = 1.f / (1.f + __expf(-(iz + my_hz + bhz)));
        float n = tanhf(inn + r * (my_hn + bhn));
        float hprev = hsm[b * HID + j];
        float hnew = (1.f - z) * n + z * hprev;
        h_out[b * HID + j] = hnew;
        short hi_ = f2bf(hnew);
        short lo_ = f2bf(hnew - bf2f(hi_));
        size_t mrow = ((size_t)b * TT + t) * 2048;
        hs_s[mrow + j] = hi_;
        hs_s[mrow + 1024 + j] = lo_;
        if (hid_out) hid_out[b * HID + j] = hnew;
    }
}

// ---------------------------------------------------------------------------
// In-place log_softmax over vocab dim of out[4096][32000].
// ---------------------------------------------------------------------------
__global__ __launch_bounds__(256) void logsoftmax_rows(float* __restrict__ out) {
    int row = blockIdx.x;
    float* p = out + (size_t)row * VOCAB;
    int tid = threadIdx.x;
    __shared__ float red[4];

    float m = -3.4e38f;
    for (int i = tid; i < VOCAB; i += 256) m = fmaxf(m, p[i]);
#pragma unroll
    for (int off = 32; off; off >>= 1) m = fmaxf(m, __shfl_xor(m, off));
    if ((tid & 63) == 0) red[tid >> 6] = m;
    __syncthreads();
    m = fmaxf(fmaxf(red[0], red[1]), fmaxf(red[2], red[3]));
    __syncthreads();

    float s = 0.f;
    for (int i = tid; i < VOCAB; i += 256) s += __expf(p[i] - m);
#pragma unroll
    for (int off = 32; off; off >>= 1) s += __shfl_xor(s, off);
    if ((tid & 63) == 0) red[tid >> 6] = s;
    __syncthreads();
    s = red[0] + red[1] + red[2] + red[3];

    float lse = m + __logf(s);
    for (int i = tid; i < VOCAB; i += 256) p[i] = p[i] - lse;
}

// ---------------------------------------------------------------------------
extern "C" void kernel_launch(void* const* d_in, const int* in_sizes, int n_in,
                              void* d_out, int out_size, void* d_ws, size_t ws_size,
                              hipStream_t stream) {
    const int*   tok  = (const int*)d_in[0];
    const float* emb  = (const float*)d_in[1];
    const float* W_ih = (const float*)d_in[2];
    const float* W_hh = (const float*)d_in[3];
    const float* b_ih = (const float*)d_in[4];
    const float* b_hh = (const float*)d_in[5];
    const float* W1   = (const float*)d_in[6];
    const float* b1   = (const float*)d_in[7];
    const float* W2   = (const float*)d_in[8];
    const float* b2   = (const float*)d_in[9];

    float* out = (float*)d_out;                       // [4096][32000] log-probs
    float* hid = out + (size_t)MROWS * VOCAB;         // [1][16][1024]

    // workspace: xp(bf16 split) | hs_s(bf16 split) | y(bf16) | gi(f32) | hA | hB  ~84MB
    short* xp   = (short*)d_ws;                           // 4096*1024
    short* hs_s = xp + (size_t)MROWS * 1024;              // 4096*2048
    short* y    = hs_s + (size_t)MROWS * 2048;            // 4096*1024
    float* gi   = (float*)(y + (size_t)MROWS * 1024);     // 4096*3072
    float* hA   = gi + (size_t)MROWS * 3 * HID;           // 16*1024
    float* hB   = hA + BB * HID;                          // 16*1024

    // 1. embedding gather + split
    gather_split<<<MROWS, 64, 0, stream>>>(tok, emb, xp);

    // 2. gi = x @ W_ih^T + b_ih   (split-A bf16 MFMA, K=512)
    gemm_mf<1, 0><<<dim3(MROWS / 128, (3 * HID) / 128), 256, 0, stream>>>(
        xp, W_ih, b_ih, gi, nullptr, MROWS, 3 * HID, EMBED);

    // 3. GRU scan (h0 = 0)
    hipMemsetAsync(hA, 0, (size_t)BB * HID * sizeof(float), stream);
    for (int t = 0; t < TT; ++t) {
        const float* hin = (t & 1) ? hB : hA;
        float* hout      = (t & 1) ? hA : hB;
        gru_step<<<HID / 4, 256, 0, stream>>>(gi, W_hh, b_hh, hin, hout, hs_s,
                                              (t == TT - 1) ? hid : nullptr, t);
    }

    // 4. y = relu(hs @ W1^T + b1)  (split-A, bf16 out)
    gemm_mf<1, 1><<<dim3(MROWS / 128, HID / 128), 256, 0, stream>>>(
        hs_s, W1, b1, nullptr, y, MROWS, HID, HID);

    // 5. logits = y @ W2^T + b2 -> d_out  (plain bf16 MFMA)
    gemm_mf<0, 0><<<dim3(MROWS / 128, VOCAB / 128), 256, 0, stream>>>(
        y, W2, b2, out, nullptr, MROWS, VOCAB, HID);

    // 6. in-place log_softmax
    logsoftmax_rows<<<MROWS, 256, 0, stream>>>(out);
}